// Round 4
// baseline (316.500 us; speedup 1.0000x reference)
//
#include <hip/hip_runtime.h>

typedef __bf16 bf16;
typedef __bf16 bf16x8 __attribute__((ext_vector_type(8)));
typedef float f32x4 __attribute__((ext_vector_type(4)));

#define NN 8192

// k-slot permutation: fragment position p (lane lg = p>>3, elem j = p&7) holds
// k = kperm(p) = (p>>3)*4 + (p&3) + ((p&4) ? 16 : 0). A-loads are dense because
// lane lg reads floats [lg*4, lg*4+4) and [16+lg*4, 16+lg*4+4). B is packed with
// the inverse permutation so the contraction pairs match exactly.
__device__ inline int pinv32(int k) {
  return ((k >> 2) & 3) * 8 + (k & 3) + ((k & 16) ? 4 : 0);
}

__device__ inline bf16x8 cvt8(float4 lo, float4 hi) {
  bf16x8 r;
  r[0] = (__bf16)lo.x; r[1] = (__bf16)lo.y; r[2] = (__bf16)lo.z; r[3] = (__bf16)lo.w;
  r[4] = (__bf16)hi.x; r[5] = (__bf16)hi.y; r[6] = (__bf16)hi.z; r[7] = (__bf16)hi.w;
  return r;
}

// ---------------- enc1: B1p[ktile][c(128)][p] = relu(nodes @ We1 + be1), k-permuted pack
__global__ __launch_bounds__(256) void k_enc1(const float* __restrict__ nodes,
                                              const float* __restrict__ We1,
                                              const float* __restrict__ be1,
                                              bf16* __restrict__ B1p) {
  __shared__ float Ns[32 * 68];
  __shared__ bf16 Os[128 * 40];   // [col][p 0..31], stride 40
  int tid = threadIdx.x;
  int r0 = blockIdx.x * 32;
  for (int idx = tid; idx < 512; idx += 256) {
    int r = idx >> 4, c4 = (idx & 15) * 4;
    *(float4*)(&Ns[r * 68 + c4]) = *(const float4*)(nodes + (r0 + r) * 64 + c4);
  }
  __syncthreads();
  int c = tid & 127, rb = tid >> 7;  // rows rb + 2k, k<16
  float acc[16];
  float b = be1[c];
#pragma unroll
  for (int k = 0; k < 16; ++k) acc[k] = b;
  for (int f = 0; f < 64; ++f) {
    float wv = We1[f * 128 + c];
#pragma unroll
    for (int k = 0; k < 16; ++k)
      acc[k] = fmaf(Ns[(rb + 2 * k) * 68 + f], wv, acc[k]);
  }
#pragma unroll
  for (int k = 0; k < 16; ++k) {
    float v = acc[k] > 0.f ? acc[k] : 0.f;
    Os[c * 40 + pinv32(rb + 2 * k)] = (bf16)v;
  }
  __syncthreads();
  int c2 = tid >> 1, h = tid & 1;
  const uint4* src = (const uint4*)(Os + c2 * 40 + h * 16);
  uint4* dst = (uint4*)(B1p + (size_t)blockIdx.x * 128 * 32 + c2 * 32 + h * 16);
  dst[0] = src[0]; dst[1] = src[1];
}

// ---------------- pass: Out[z][r][c] = A[:, krange] @ Bpacked. No LDS, no barriers.
// Block: 4 waves = 2 rowg x 2 colg; wave = 32 rows x NCG*16 cols; block covers all COLS=32*NCG.
// Dense A loads (16 fully-used lines per instr) + permuted-k B pack. A,B dbuf 1 step ahead.
struct AF { float4 q[4]; };

template <int NCG, int MINW>
__global__ __launch_bounds__(256, MINW) void k_pass(const float* __restrict__ A,
                                                    const bf16* __restrict__ Bp,
                                                    float* __restrict__ Out,
                                                    int KL) {
  constexpr int COLS = 32 * NCG;
  int tid = threadIdx.x;
  int lane = tid & 63, w = tid >> 6;
  int rowg = w >> 1, colg = w & 1;
  int l15 = lane & 15, lg = lane >> 4;
  int r0 = blockIdx.x * 64 + rowg * 32;
  int c0 = colg * (NCG * 16);
  int kbase = blockIdx.z * KL;
  const float* pa0 = A + (size_t)(r0 + l15) * NN + kbase + lg * 4;
  const float* pa1 = pa0 + (size_t)16 * NN;
  const bf16* bbase = Bp + ((size_t)(kbase >> 5) * COLS + c0 + l15) * 32 + lg * 8;

  f32x4 acc[2][NCG];
#pragma unroll
  for (int m = 0; m < 2; ++m)
#pragma unroll
    for (int cg = 0; cg < NCG; ++cg) acc[m][cg] = (f32x4){0.f, 0.f, 0.f, 0.f};

  auto LDA = [&](int kt, AF& f) {
    f.q[0] = *(const float4*)(pa0 + kt);
    f.q[1] = *(const float4*)(pa0 + kt + 16);
    f.q[2] = *(const float4*)(pa1 + kt);
    f.q[3] = *(const float4*)(pa1 + kt + 16);
  };
  auto LDB = [&](int kt, uint4* b) {
    const bf16* p = bbase + (size_t)(kt >> 5) * (COLS * 32);
#pragma unroll
    for (int cg = 0; cg < NCG; ++cg) b[cg] = *(const uint4*)(p + cg * 512);
  };
  auto CMP = [&](const AF& f, const uint4* b) {
    bf16x8 a0 = cvt8(f.q[0], f.q[1]);
    bf16x8 a1 = cvt8(f.q[2], f.q[3]);
#pragma unroll
    for (int cg = 0; cg < NCG; ++cg) {
      bf16x8 bfr = __builtin_bit_cast(bf16x8, b[cg]);
      acc[0][cg] = __builtin_amdgcn_mfma_f32_16x16x32_bf16(a0, bfr, acc[0][cg], 0, 0, 0);
      acc[1][cg] = __builtin_amdgcn_mfma_f32_16x16x32_bf16(a1, bfr, acc[1][cg], 0, 0, 0);
    }
  };

  AF a0f, a1f;
  uint4 b0[NCG], b1[NCG];
  LDA(0, a0f);
  LDB(0, b0);
  int ktail = KL - 64;
  int kt = 0;
  for (; kt < ktail; kt += 64) {
    LDA(kt + 32, a1f);
    LDB(kt + 32, b1);
    CMP(a0f, b0);
    LDA(kt + 64, a0f);
    LDB(kt + 64, b0);
    CMP(a1f, b1);
  }
  LDA(kt + 32, a1f);
  LDB(kt + 32, b1);
  CMP(a0f, b0);
  CMP(a1f, b1);

  float* out = Out + (size_t)blockIdx.z * NN * COLS;
#pragma unroll
  for (int m = 0; m < 2; ++m)
#pragma unroll
    for (int cg = 0; cg < NCG; ++cg)
#pragma unroll
      for (int i = 0; i < 4; ++i)
        out[(size_t)(r0 + m * 16 + lg * 4 + i) * COLS + c0 + cg * 16 + l15] = acc[m][cg][i];
}

// ---------------- mid: B3p[ktile][c(64)][p] = relu(sum_z X2p @ We2 + be2), k-permuted pack
__global__ __launch_bounds__(256) void k_mid(const float* __restrict__ X2p,
                                             const float* __restrict__ We2,
                                             const float* __restrict__ be2,
                                             bf16* __restrict__ B3p, int KS) {
  __shared__ float X2s[32 * 128];
  __shared__ bf16 Os[64 * 40];
  int tid = threadIdx.x;
  int r0 = blockIdx.x * 32;
  for (int idx = tid; idx < 1024; idx += 256) {
    int r = idx >> 5, c4 = (idx & 31) * 4;
    float4 u = {0.f, 0.f, 0.f, 0.f};
    for (int p = 0; p < KS; ++p) {
      float4 v = *(const float4*)(X2p + (size_t)p * NN * 128 + (size_t)(r0 + r) * 128 + c4);
      u.x += v.x; u.y += v.y; u.z += v.z; u.w += v.w;
    }
    *(float4*)(&X2s[r * 128 + c4]) = u;
  }
  __syncthreads();
  int c = tid & 63, rb = tid >> 6;  // rows rb + 4k, k<8
  float acc[8];
  float b = be2[c];
#pragma unroll
  for (int k = 0; k < 8; ++k) acc[k] = b;
  for (int j = 0; j < 128; ++j) {
    float wv = We2[j * 64 + c];
#pragma unroll
    for (int k = 0; k < 8; ++k)
      acc[k] = fmaf(X2s[(rb + 4 * k) * 128 + j], wv, acc[k]);
  }
#pragma unroll
  for (int k = 0; k < 8; ++k) {
    float v = acc[k] > 0.f ? acc[k] : 0.f;
    Os[c * 40 + pinv32(rb + 4 * k)] = (bf16)v;
  }
  __syncthreads();
  int c2 = tid >> 2, h = tid & 3;
  const uint4* src = (const uint4*)(Os + c2 * 40 + h * 8);
  uint4* dst = (uint4*)(B3p + (size_t)blockIdx.x * 64 * 32 + c2 * 32 + h * 8);
  dst[0] = src[0];
}

// ---------------- head
__global__ __launch_bounds__(256) void k_head(const float* __restrict__ X4p,
                                              const float* __restrict__ actions,
                                              const float* __restrict__ Weo,
                                              const float* __restrict__ beo,
                                              const float* __restrict__ Wc1,
                                              const float* __restrict__ bc1,
                                              const float* __restrict__ Wc2,
                                              const float* __restrict__ bc2,
                                              const float* __restrict__ Wq,
                                              const float* __restrict__ bq,
                                              float* __restrict__ q, int KS) {
  __shared__ float X4s[32 * 65];
  __shared__ float hs[32 * 81];
  __shared__ float h1s[32 * 129];
  __shared__ float h2s[32 * 65];
  int tid = threadIdx.x;
  int r0 = blockIdx.x * 32;
  for (int idx = tid; idx < 2048; idx += 256) {
    int r = idx >> 6, c = idx & 63;
    float s = 0.f;
    for (int p = 0; p < KS; ++p)
      s += X4p[(size_t)p * NN * 64 + (size_t)(r0 + r) * 64 + c];
    X4s[r * 65 + c] = s;
  }
  for (int idx = tid; idx < 512; idx += 256) {
    int r = idx >> 4, a = idx & 15;
    hs[r * 81 + 64 + a] = actions[(r0 + r) * 16 + a];
  }
  __syncthreads();
  {
    int c = tid & 63, rb = tid >> 6;
    float acc[8];
    float b = beo[c];
#pragma unroll
    for (int k = 0; k < 8; ++k) acc[k] = b;
    for (int j = 0; j < 64; ++j) {
      float wv = Weo[j * 64 + c];
#pragma unroll
      for (int k = 0; k < 8; ++k)
        acc[k] = fmaf(X4s[(rb + 4 * k) * 65 + j], wv, acc[k]);
    }
#pragma unroll
    for (int k = 0; k < 8; ++k) hs[(rb + 4 * k) * 81 + c] = acc[k];
  }
  __syncthreads();
  {
    int c = tid & 127, rb = tid >> 7;
    float acc[16];
    float b = bc1[c];
#pragma unroll
    for (int k = 0; k < 16; ++k) acc[k] = b;
    for (int j = 0; j < 80; ++j) {
      float wv = Wc1[j * 128 + c];
#pragma unroll
      for (int k = 0; k < 16; ++k)
        acc[k] = fmaf(hs[(rb + 2 * k) * 81 + j], wv, acc[k]);
    }
#pragma unroll
    for (int k = 0; k < 16; ++k) {
      float v = acc[k] > 0.f ? acc[k] : 0.f;
      h1s[(rb + 2 * k) * 129 + c] = v;
    }
  }
  __syncthreads();
  {
    int c = tid & 63, rb = tid >> 6;
    float acc[8];
    float b = bc2[c];
#pragma unroll
    for (int k = 0; k < 8; ++k) acc[k] = b;
    for (int j = 0; j < 128; ++j) {
      float wv = Wc2[j * 64 + c];
#pragma unroll
      for (int k = 0; k < 8; ++k)
        acc[k] = fmaf(h1s[(rb + 4 * k) * 129 + j], wv, acc[k]);
    }
#pragma unroll
    for (int k = 0; k < 8; ++k) {
      float v = acc[k] > 0.f ? acc[k] : 0.f;
      h2s[(rb + 4 * k) * 65 + c] = v;
    }
  }
  __syncthreads();
  if (tid < 32) {
    float acc = bq[0];
    for (int j = 0; j < 64; ++j) acc = fmaf(h2s[tid * 65 + j], Wq[j], acc);
    q[r0 + tid] = acc;
  }
}

extern "C" void kernel_launch(void* const* d_in, const int* in_sizes, int n_in,
                              void* d_out, int out_size, void* d_ws, size_t ws_size,
                              hipStream_t stream) {
  const float* nodes = (const float*)d_in[0];
  const float* A = (const float*)d_in[2];
  const float* actions = (const float*)d_in[3];
  const float* We1 = (const float*)d_in[4];
  const float* be1 = (const float*)d_in[5];
  const float* We2 = (const float*)d_in[6];
  const float* be2 = (const float*)d_in[7];
  const float* Weo = (const float*)d_in[8];
  const float* beo = (const float*)d_in[9];
  const float* Wc1 = (const float*)d_in[10];
  const float* bc1 = (const float*)d_in[11];
  const float* Wc2 = (const float*)d_in[12];
  const float* bc2 = (const float*)d_in[13];
  const float* Wq = (const float*)d_in[14];
  const float* bq = (const float*)d_in[15];
  float* q = (float*)d_out;

  const size_t MB = 1ull << 20;
  int KS = 16;
  if (ws_size < 3 * MB + 16 * 6 * MB) KS = 8;
  if (ws_size < 3 * MB + 8 * 6 * MB) KS = 4;
  if (ws_size < 3 * MB + 4 * 6 * MB) KS = 2;

  char* ws = (char*)d_ws;
  bf16* B1p = (bf16*)(ws);                                   // 2 MB [256][128][32]
  bf16* B3p = (bf16*)(ws + 2 * MB);                          // 1 MB [256][64][32]
  float* X2p = (float*)(ws + 3 * MB);                        // KS * 4 MB
  float* X4p = (float*)(ws + 3 * MB + (size_t)KS * 4 * MB);  // KS * 2 MB

  int KL = NN / KS;
  k_enc1<<<256, 256, 0, stream>>>(nodes, We1, be1, B1p);
  k_pass<4, 4><<<dim3(128, 1, KS), 256, 0, stream>>>(A, B1p, X2p, KL);
  k_mid<<<256, 256, 0, stream>>>(X2p, We2, be2, B3p, KS);
  k_pass<2, 5><<<dim3(128, 1, KS), 256, 0, stream>>>(A, B3p, X4p, KL);
  k_head<<<256, 256, 0, stream>>>(X4p, actions, Weo, beo, Wc1, bc1, Wc2, bc2, Wq, bq, q, KS);
}

// Round 5
// 276.165 us; speedup vs baseline: 1.1461x; 1.1461x over previous
//
#include <hip/hip_runtime.h>

typedef __bf16 bf16;
typedef __bf16 bf16x8 __attribute__((ext_vector_type(8)));
typedef float f32x4 __attribute__((ext_vector_type(4)));

#define NN 8192

__device__ inline bf16x8 cvt8(float4 lo, float4 hi) {
  bf16x8 r;
  r[0] = (__bf16)lo.x; r[1] = (__bf16)lo.y; r[2] = (__bf16)lo.z; r[3] = (__bf16)lo.w;
  r[4] = (__bf16)hi.x; r[5] = (__bf16)hi.y; r[6] = (__bf16)hi.z; r[7] = (__bf16)hi.w;
  return r;
}

__device__ inline void gload16(const float* g, float* l) {
  __builtin_amdgcn_global_load_lds(
      (const __attribute__((address_space(1))) unsigned int*)g,
      (__attribute__((address_space(3))) unsigned int*)l, 16, 0, 0);
}

// ---------------- enc1: B1p[ktile][c(128)][k&31] = relu(nodes @ We1 + be1), identity pack
__global__ __launch_bounds__(256) void k_enc1(const float* __restrict__ nodes,
                                              const float* __restrict__ We1,
                                              const float* __restrict__ be1,
                                              bf16* __restrict__ B1p) {
  __shared__ float Ns[32 * 68];
  __shared__ bf16 Os[128 * 40];
  int tid = threadIdx.x;
  int r0 = blockIdx.x * 32;
  for (int idx = tid; idx < 512; idx += 256) {
    int r = idx >> 4, c4 = (idx & 15) * 4;
    *(float4*)(&Ns[r * 68 + c4]) = *(const float4*)(nodes + (r0 + r) * 64 + c4);
  }
  __syncthreads();
  int c = tid & 127, rb = tid >> 7;  // rows rb + 2k, k<16
  float acc[16];
  float b = be1[c];
#pragma unroll
  for (int k = 0; k < 16; ++k) acc[k] = b;
  for (int f = 0; f < 64; ++f) {
    float wv = We1[f * 128 + c];
#pragma unroll
    for (int k = 0; k < 16; ++k)
      acc[k] = fmaf(Ns[(rb + 2 * k) * 68 + f], wv, acc[k]);
  }
#pragma unroll
  for (int k = 0; k < 16; ++k) {
    float v = acc[k] > 0.f ? acc[k] : 0.f;
    Os[c * 40 + rb + 2 * k] = (bf16)v;
  }
  __syncthreads();
  int c2 = tid >> 1, h = tid & 1;
  const uint4* src = (const uint4*)(Os + c2 * 40 + h * 16);
  uint4* dst = (uint4*)(B1p + (size_t)blockIdx.x * 128 * 32 + c2 * 32 + h * 16);
  dst[0] = src[0]; dst[1] = src[1];
}

// ---------------- pass: Out[z][r][c] = A[:, krange] @ Bpacked.
// BM=32, BK=128. A staged f32 into LDS via global_load_lds with XOR slot-swizzle
// applied at the global source (row-contiguous 512B reads -> channel spread);
// ds_read applies the same XOR so fragments get true k order. B register-direct.
template <int NF>
__global__ __launch_bounds__(256, 4) void k_pass(const float* __restrict__ A,
                                                 const bf16* __restrict__ Bp,
                                                 float* __restrict__ Out,
                                                 int KL) {
  constexpr int COLS = NF * 64;
  __shared__ float Abuf[2][4096];  // [32 rows][128 f32], 16 KB per buffer
  int tid = threadIdx.x;
  int lane = tid & 63, w = tid >> 6;
  int l15 = lane & 15, lg = lane >> 4;
  int r0 = blockIdx.x * 32;
  int kbase = blockIdx.y * KL;

  // staging: iter j, thread stages 16B chunk c=tid&31 of row j*8 + tid/32.
  // source col pre-swizzled: slot (32B) s -> s ^ (row&7)
  const float* pstg[4];
#pragma unroll
  for (int j = 0; j < 4; ++j) {
    int row = j * 8 + (tid >> 5);
    int c = tid & 31;
    int col = (((c >> 1) ^ (row & 7)) << 3) + ((c & 1) << 2);
    pstg[j] = A + (size_t)(r0 + row) * NN + kbase + col;
  }
  const bf16* pb[NF];
#pragma unroll
  for (int nf = 0; nf < NF; ++nf) {
    int col = w * (NF * 16) + nf * 16 + l15;
    pb[nf] = Bp + (size_t)(kbase >> 5) * (COLS * 32) + col * 32 + lg * 8;
  }

  f32x4 acc[2][NF];
#pragma unroll
  for (int m = 0; m < 2; ++m)
#pragma unroll
    for (int nf = 0; nf < NF; ++nf) acc[m][nf] = (f32x4){0.f, 0.f, 0.f, 0.f};

  int NSTEP = KL >> 7;  // BK=128
  // prologue: stage step 0 into buf 0
#pragma unroll
  for (int j = 0; j < 4; ++j)
    gload16(pstg[j], &Abuf[0][j * 1024 + tid * 4]);

  for (int s = 0; s < NSTEP; ++s) {
    __syncthreads();  // staging for step s complete; prev ds_reads drained
    int cur = s & 1;
    // B loads for this step (issued first so their waits don't drain staging)
    uint4 b[4][NF];
#pragma unroll
    for (int kf = 0; kf < 4; ++kf)
#pragma unroll
      for (int nf = 0; nf < NF; ++nf)
        b[kf][nf] = *(const uint4*)(pb[nf] + (size_t)(s * 4 + kf) * (COLS * 32));
    // stage step s+1 into the other buffer (stays in flight across compute)
    if (s + 1 < NSTEP) {
#pragma unroll
      for (int j = 0; j < 4; ++j)
        gload16(pstg[j] + (s + 1) * 128, &Abuf[cur ^ 1][j * 1024 + tid * 4]);
    }
    // compute from Abuf[cur]
#pragma unroll
    for (int kf = 0; kf < 4; ++kf) {
#pragma unroll
      for (int m = 0; m < 2; ++m) {
        int row = m * 16 + l15;
        int sl = (((kf * 4 + lg) ^ (row & 7)) << 3);
        const float* ap = &Abuf[cur][row * 128 + sl];
        float4 r1 = *(const float4*)ap;
        float4 r2 = *(const float4*)(ap + 4);
        bf16x8 a = cvt8(r1, r2);
#pragma unroll
        for (int nf = 0; nf < NF; ++nf)
          acc[m][nf] = __builtin_amdgcn_mfma_f32_16x16x32_bf16(
              a, __builtin_bit_cast(bf16x8, b[kf][nf]), acc[m][nf], 0, 0, 0);
      }
    }
  }

  float* out = Out + (size_t)blockIdx.y * NN * COLS;
#pragma unroll
  for (int m = 0; m < 2; ++m)
#pragma unroll
    for (int nf = 0; nf < NF; ++nf)
#pragma unroll
      for (int i = 0; i < 4; ++i)
        out[(size_t)(r0 + m * 16 + lg * 4 + i) * COLS + w * (NF * 16) + nf * 16 + l15] =
            acc[m][nf][i];
}

// ---------------- mid: B3p[ktile][c(64)][k&31] = relu(sum_z X2p @ We2 + be2), identity pack
__global__ __launch_bounds__(256) void k_mid(const float* __restrict__ X2p,
                                             const float* __restrict__ We2,
                                             const float* __restrict__ be2,
                                             bf16* __restrict__ B3p, int KS) {
  __shared__ float X2s[32 * 128];
  __shared__ bf16 Os[64 * 40];
  int tid = threadIdx.x;
  int r0 = blockIdx.x * 32;
  for (int idx = tid; idx < 1024; idx += 256) {
    int r = idx >> 5, c4 = (idx & 31) * 4;
    float4 u = {0.f, 0.f, 0.f, 0.f};
    for (int p = 0; p < KS; ++p) {
      float4 v = *(const float4*)(X2p + (size_t)p * NN * 128 + (size_t)(r0 + r) * 128 + c4);
      u.x += v.x; u.y += v.y; u.z += v.z; u.w += v.w;
    }
    *(float4*)(&X2s[r * 128 + c4]) = u;
  }
  __syncthreads();
  int c = tid & 63, rb = tid >> 6;  // rows rb + 4k, k<8
  float acc[8];
  float b = be2[c];
#pragma unroll
  for (int k = 0; k < 8; ++k) acc[k] = b;
  for (int j = 0; j < 128; ++j) {
    float wv = We2[j * 64 + c];
#pragma unroll
    for (int k = 0; k < 8; ++k)
      acc[k] = fmaf(X2s[(rb + 4 * k) * 128 + j], wv, acc[k]);
  }
#pragma unroll
  for (int k = 0; k < 8; ++k) {
    float v = acc[k] > 0.f ? acc[k] : 0.f;
    Os[c * 40 + rb + 4 * k] = (bf16)v;
  }
  __syncthreads();
  int c2 = tid >> 2, h = tid & 3;
  const uint4* src = (const uint4*)(Os + c2 * 40 + h * 8);
  uint4* dst = (uint4*)(B3p + (size_t)blockIdx.x * 64 * 32 + c2 * 32 + h * 8);
  dst[0] = src[0];
}

// ---------------- head
__global__ __launch_bounds__(256) void k_head(const float* __restrict__ X4p,
                                              const float* __restrict__ actions,
                                              const float* __restrict__ Weo,
                                              const float* __restrict__ beo,
                                              const float* __restrict__ Wc1,
                                              const float* __restrict__ bc1,
                                              const float* __restrict__ Wc2,
                                              const float* __restrict__ bc2,
                                              const float* __restrict__ Wq,
                                              const float* __restrict__ bq,
                                              float* __restrict__ q, int KS) {
  __shared__ float X4s[32 * 65];
  __shared__ float hs[32 * 81];
  __shared__ float h1s[32 * 129];
  __shared__ float h2s[32 * 65];
  int tid = threadIdx.x;
  int r0 = blockIdx.x * 32;
  for (int idx = tid; idx < 2048; idx += 256) {
    int r = idx >> 6, c = idx & 63;
    float s = 0.f;
    for (int p = 0; p < KS; ++p)
      s += X4p[(size_t)p * NN * 64 + (size_t)(r0 + r) * 64 + c];
    X4s[r * 65 + c] = s;
  }
  for (int idx = tid; idx < 512; idx += 256) {
    int r = idx >> 4, a = idx & 15;
    hs[r * 81 + 64 + a] = actions[(r0 + r) * 16 + a];
  }
  __syncthreads();
  {
    int c = tid & 63, rb = tid >> 6;
    float acc[8];
    float b = beo[c];
#pragma unroll
    for (int k = 0; k < 8; ++k) acc[k] = b;
    for (int j = 0; j < 64; ++j) {
      float wv = Weo[j * 64 + c];
#pragma unroll
      for (int k = 0; k < 8; ++k)
        acc[k] = fmaf(X4s[(rb + 4 * k) * 65 + j], wv, acc[k]);
    }
#pragma unroll
    for (int k = 0; k < 8; ++k) hs[(rb + 4 * k) * 81 + c] = acc[k];
  }
  __syncthreads();
  {
    int c = tid & 127, rb = tid >> 7;
    float acc[16];
    float b = bc1[c];
#pragma unroll
    for (int k = 0; k < 16; ++k) acc[k] = b;
    for (int j = 0; j < 80; ++j) {
      float wv = Wc1[j * 128 + c];
#pragma unroll
      for (int k = 0; k < 16; ++k)
        acc[k] = fmaf(hs[(rb + 2 * k) * 81 + j], wv, acc[k]);
    }
#pragma unroll
    for (int k = 0; k < 16; ++k) {
      float v = acc[k] > 0.f ? acc[k] : 0.f;
      h1s[(rb + 2 * k) * 129 + c] = v;
    }
  }
  __syncthreads();
  {
    int c = tid & 63, rb = tid >> 6;
    float acc[8];
    float b = bc2[c];
#pragma unroll
    for (int k = 0; k < 8; ++k) acc[k] = b;
    for (int j = 0; j < 128; ++j) {
      float wv = Wc2[j * 64 + c];
#pragma unroll
      for (int k = 0; k < 8; ++k)
        acc[k] = fmaf(h1s[(rb + 4 * k) * 129 + j], wv, acc[k]);
    }
#pragma unroll
    for (int k = 0; k < 8; ++k) {
      float v = acc[k] > 0.f ? acc[k] : 0.f;
      h2s[(rb + 4 * k) * 65 + c] = v;
    }
  }
  __syncthreads();
  if (tid < 32) {
    float acc = bq[0];
    for (int j = 0; j < 64; ++j) acc = fmaf(h2s[tid * 65 + j], Wq[j], acc);
    q[r0 + tid] = acc;
  }
}

extern "C" void kernel_launch(void* const* d_in, const int* in_sizes, int n_in,
                              void* d_out, int out_size, void* d_ws, size_t ws_size,
                              hipStream_t stream) {
  const float* nodes = (const float*)d_in[0];
  const float* A = (const float*)d_in[2];
  const float* actions = (const float*)d_in[3];
  const float* We1 = (const float*)d_in[4];
  const float* be1 = (const float*)d_in[5];
  const float* We2 = (const float*)d_in[6];
  const float* be2 = (const float*)d_in[7];
  const float* Weo = (const float*)d_in[8];
  const float* beo = (const float*)d_in[9];
  const float* Wc1 = (const float*)d_in[10];
  const float* bc1 = (const float*)d_in[11];
  const float* Wc2 = (const float*)d_in[12];
  const float* bc2 = (const float*)d_in[13];
  const float* Wq = (const float*)d_in[14];
  const float* bq = (const float*)d_in[15];
  float* q = (float*)d_out;

  const size_t MB = 1ull << 20;
  int KS = 4;
  if (ws_size < 3 * MB + 4 * 6 * MB) KS = 2;

  char* ws = (char*)d_ws;
  bf16* B1p = (bf16*)(ws);                                   // 2 MB [256][128][32]
  bf16* B3p = (bf16*)(ws + 2 * MB);                          // 1 MB [256][64][32]
  float* X2p = (float*)(ws + 3 * MB);                        // KS * 4 MB
  float* X4p = (float*)(ws + 3 * MB + (size_t)KS * 4 * MB);  // KS * 2 MB

  int KL = NN / KS;
  k_enc1<<<256, 256, 0, stream>>>(nodes, We1, be1, B1p);
  k_pass<2><<<dim3(256, KS), 256, 0, stream>>>(A, B1p, X2p, KL);
  k_mid<<<256, 256, 0, stream>>>(X2p, We2, be2, B3p, KS);
  k_pass<1><<<dim3(256, KS), 256, 0, stream>>>(A, B3p, X4p, KL);
  k_head<<<256, 256, 0, stream>>>(X4p, actions, Weo, beo, Wc1, bc1, Wc2, bc2, Wq, bq, q, KS);
}